// Round 1
// baseline (39008.560 us; speedup 1.0000x reference)
//
#include <hip/hip_runtime.h>

#define ALPHA 0.1f

constexpr int T  = 1024;
constexpr int B  = 32;
constexpr int I  = 64;
constexpr int H  = 1024;
constexpr int OF = 64;
constexpr int OC = 8;
constexpr int K  = H + I;      // 1088: h2h (1024) + i2h (64) folded into one dot
constexpr int NKK = K / 32;    // 34 k-slices of 32
constexpr int NGROUPS = 16;    // sync groups
constexpr int NMEMB   = 16;    // workgroups per group
constexpr int BPG = B / NGROUPS;        // 2 batches per group
constexpr int ROWS_PER_WG = H / NMEMB;  // 64 rows per workgroup
constexpr long long OUT1_OFF = (long long)T * B * OF;          // output_ctx offset
constexpr long long OUT2_OFF = (long long)T * B * (OF + OC);   // rate_all offset
constexpr int CNT_STRIDE = 32; // pad counters to 128B to avoid line contention

// ---------------------------------------------------------------------------
// Recurrence: persistent kernel, 256 WGs x 512 threads.
//   group g = bid % 16  (round-robin XCD mapping keeps a group on one XCD)
//   member m = bid / 16 owns hidden rows [m*64, m*64+64) for the group's
//   2 batches. Weights register-stationary: w[4][34] fp32 per thread.
//   thread = (rg = tid>>5 in [0,16), ks = tid&31): rows rg*4..rg*4+3,
//   k-slice {kk*32 + ks}. r exchange via rate_all (d_out) + atomic counters.
// ---------------------------------------------------------------------------
__global__ __launch_bounds__(512, 2) void rnn_recur(
    const float* __restrict__ input_sig, const float* __restrict__ rate0,
    const float* __restrict__ i2h_w, const float* __restrict__ i2h_b,
    const float* __restrict__ h2h_w, const float* __restrict__ h2h_b,
    float* __restrict__ rate_all, unsigned* __restrict__ cnt)
{
  const int tid = threadIdx.x;
  const int bid = blockIdx.x;
  const int g  = bid & (NGROUPS - 1);
  const int m  = bid >> 4;
  const int j0 = m * ROWS_PER_WG;
  const int rg = tid >> 5;
  const int ks = tid & 31;
  const int bG = g * BPG;   // first batch of this group

  __shared__ float r_lds[BPG * K];  // [2][1088] fp32, bank = k%32 = ks

  // ---- register-stationary weights (h2h rows + i2h rows appended at k>=1024)
  float w[4][NKK];
  float bsum[4];
#pragma unroll
  for (int jj = 0; jj < 4; ++jj) {
    const int j = j0 + rg * 4 + jj;
    bsum[jj] = h2h_b[j] + i2h_b[j];
#pragma unroll
    for (int kk = 0; kk < NKK; ++kk) {
      const int k = kk * 32 + ks;
      w[jj][kk] = (kk < 32) ? h2h_w[j * H + k] : i2h_w[j * I + (k - H)];
    }
  }

  // ---- initial stage: r_{-1} = rate0 ; input_sig[0]
  {
    const int b = tid >> 8, kq = tid & 255;
    float4 v = *(const float4*)(rate0 + (bG + b) * H + kq * 4);
    *(float4*)(&r_lds[b * K + kq * 4]) = v;
    if (tid < 32) {
      const int b2 = tid >> 4, iq = tid & 15;
      float4 u = *(const float4*)(input_sig + (long long)(bG + b2) * I + iq * 4);
      *(float4*)(&r_lds[b2 * K + H + iq * 4]) = u;
    }
  }
  __syncthreads();

  for (int t = 0; t < T; ++t) {
    float acc0[4] = {0.f, 0.f, 0.f, 0.f};
    float acc1[4] = {0.f, 0.f, 0.f, 0.f};
#pragma unroll
    for (int kk = 0; kk < NKK; ++kk) {
      const float r0 = r_lds[kk * 32 + ks];
      const float r1 = r_lds[K + kk * 32 + ks];
#pragma unroll
      for (int jj = 0; jj < 4; ++jj) {
        acc0[jj] = fmaf(w[jj][kk], r0, acc0[jj]);
        acc1[jj] = fmaf(w[jj][kk], r1, acc1[jj]);
      }
    }
    // butterfly reduce across the 32 ks lanes (masks <=16 stay in each half)
#pragma unroll
    for (int off = 16; off >= 1; off >>= 1) {
#pragma unroll
      for (int jj = 0; jj < 4; ++jj) {
        acc0[jj] += __shfl_xor(acc0[jj], off, 64);
        acc1[jj] += __shfl_xor(acc1[jj], off, 64);
      }
    }
    // 8 owner lanes per 32-lane slice apply bias + tanh + leaky update
    if (ks < 8) {
      const int bsel = ks >> 2, jj = ks & 3;
      const float pre = (bsel == 0)
          ? ((jj == 0) ? acc0[0] : (jj == 1) ? acc0[1] : (jj == 2) ? acc0[2] : acc0[3])
          : ((jj == 0) ? acc1[0] : (jj == 1) ? acc1[1] : (jj == 2) ? acc1[2] : acc1[3]);
      const float bias = (jj == 0) ? bsum[0] : (jj == 1) ? bsum[1]
                       : (jj == 2) ? bsum[2] : bsum[3];
      const int j = j0 + rg * 4 + jj;
      const float rold = r_lds[bsel * K + j];
      const float rnew = (1.0f - ALPHA) * rold + ALPHA * tanhf(pre + bias);
      rate_all[((long long)t * B + (bG + bsel)) * H + j] = rnew;
    }

    if (t + 1 < T) {
      // ---- group sync: release own slice, wait for all 16 members
      __threadfence();
      __syncthreads();
      if (tid == 0) {
        __hip_atomic_fetch_add(&cnt[g * CNT_STRIDE], 1u,
                               __ATOMIC_RELEASE, __HIP_MEMORY_SCOPE_AGENT);
        const unsigned target = (unsigned)NMEMB * (unsigned)(t + 1);
        while (__hip_atomic_load(&cnt[g * CNT_STRIDE],
                                 __ATOMIC_ACQUIRE, __HIP_MEMORY_SCOPE_AGENT) < target) {
          __builtin_amdgcn_s_sleep(2);
        }
      }
      __syncthreads();
      // ---- restage r_t (+ input_sig[t+1]) into LDS
      {
        const int b = tid >> 8, kq = tid & 255;
        float4 v = *(const float4*)(rate_all + ((long long)t * B + bG + b) * H + kq * 4);
        *(float4*)(&r_lds[b * K + kq * 4]) = v;
        if (tid < 32) {
          const int b2 = tid >> 4, iq = tid & 15;
          float4 u = *(const float4*)(input_sig + ((long long)(t + 1) * B + bG + b2) * I + iq * 4);
          *(float4*)(&r_lds[b2 * K + H + iq * 4]) = u;
        }
      }
      __syncthreads();
    }
  }
}

// ---------------------------------------------------------------------------
// Readout: C[32768,72] = rate_all[32768,1024] x [h2o_w;h2o_ctx_w]^T + bias
// 256 blocks x 256 threads, 128 rows/block, h-chunks of 128 staged in LDS.
// Thread tile: 4 rows x 9 outputs (rb = tid&31 row-lane, og = tid>>5).
// ---------------------------------------------------------------------------
__global__ __launch_bounds__(256) void rnn_readout(
    const float* __restrict__ rate_all,
    const float* __restrict__ h2o_w, const float* __restrict__ h2o_b,
    const float* __restrict__ h2o_ctx_w, const float* __restrict__ h2o_ctx_b,
    float* __restrict__ out0, float* __restrict__ out1)
{
  constexpr int RB = 128;   // rows per block
  constexpr int HC = 128;   // h chunk
  constexpr int SR = HC + 1; // padded stride -> conflict-free reads
  __shared__ float rl[RB * SR];   // 66 KB
  __shared__ float wl[72 * SR];   // 37 KB

  const int tid = threadIdx.x;
  const long long row0 = (long long)blockIdx.x * RB;
  const int rb = tid & 31, og = tid >> 5;

  float acc[4][9];
#pragma unroll
  for (int c = 0; c < 4; ++c)
#pragma unroll
    for (int i = 0; i < 9; ++i) acc[c][i] = 0.f;

  for (int hc = 0; hc < H / HC; ++hc) {
    // stage r chunk: 128 rows x 128 h = 4096 float4, 16 per thread
#pragma unroll
    for (int i = 0; i < 16; ++i) {
      const int q = i * 256 + tid;
      const int row = q >> 5, hq = q & 31;
      float4 v = *(const float4*)(rate_all + (row0 + row) * H + hc * HC + hq * 4);
      float* d = &rl[row * SR + hq * 4];
      d[0] = v.x; d[1] = v.y; d[2] = v.z; d[3] = v.w;
    }
    // stage w chunk: 72 x 128 = 2304 float4, 9 per thread
#pragma unroll
    for (int i = 0; i < 9; ++i) {
      const int q = i * 256 + tid;
      const int o = q >> 5, hq = q & 31;
      const float* src = (o < OF) ? (h2o_w + (long long)o * H)
                                  : (h2o_ctx_w + (long long)(o - OF) * H);
      float4 v = *(const float4*)(src + hc * HC + hq * 4);
      float* d = &wl[o * SR + hq * 4];
      d[0] = v.x; d[1] = v.y; d[2] = v.z; d[3] = v.w;
    }
    __syncthreads();

#pragma unroll 4
    for (int h = 0; h < HC; ++h) {
      const float r0 = rl[(rb)      * SR + h];
      const float r1 = rl[(rb + 32) * SR + h];
      const float r2 = rl[(rb + 64) * SR + h];
      const float r3 = rl[(rb + 96) * SR + h];
#pragma unroll
      for (int i = 0; i < 9; ++i) {
        const float wv = wl[(og * 9 + i) * SR + h];
        acc[0][i] = fmaf(r0, wv, acc[0][i]);
        acc[1][i] = fmaf(r1, wv, acc[1][i]);
        acc[2][i] = fmaf(r2, wv, acc[2][i]);
        acc[3][i] = fmaf(r3, wv, acc[3][i]);
      }
    }
    __syncthreads();
  }

#pragma unroll
  for (int c = 0; c < 4; ++c) {
    const long long row = row0 + rb + 32 * c;
#pragma unroll
    for (int i = 0; i < 9; ++i) {
      const int o = og * 9 + i;
      if (o < OF) out0[row * OF + o] = acc[c][i] + h2o_b[o];
      else        out1[row * OC + (o - OF)] = acc[c][i] + h2o_ctx_b[o - OF];
    }
  }
}

extern "C" void kernel_launch(void* const* d_in, const int* in_sizes, int n_in,
                              void* d_out, int out_size, void* d_ws, size_t ws_size,
                              hipStream_t stream) {
  (void)in_sizes; (void)n_in; (void)d_ws; (void)ws_size; (void)out_size;
  const float* input_sig = (const float*)d_in[0];
  const float* rate0     = (const float*)d_in[1];
  const float* i2h_w     = (const float*)d_in[2];
  const float* i2h_b     = (const float*)d_in[3];
  const float* h2h_w     = (const float*)d_in[4];
  const float* h2h_b     = (const float*)d_in[5];
  const float* h2o_w     = (const float*)d_in[6];
  const float* h2o_b     = (const float*)d_in[7];
  const float* h2o_ctx_w = (const float*)d_in[8];
  const float* h2o_ctx_b = (const float*)d_in[9];

  float* out      = (float*)d_out;
  float* out0     = out;
  float* out1     = out + OUT1_OFF;
  float* rate_all = out + OUT2_OFF;
  // sync counters live in the first 2KB of out0 during the recurrence;
  // the readout kernel overwrites that region with real outputs afterwards.
  unsigned* cnt = (unsigned*)d_out;

  hipMemsetAsync(d_out, 0, NGROUPS * CNT_STRIDE * sizeof(unsigned), stream);
  hipLaunchKernelGGL(rnn_recur, dim3(NGROUPS * NMEMB), dim3(512), 0, stream,
                     input_sig, rate0, i2h_w, i2h_b, h2h_w, h2h_b, rate_all, cnt);
  hipLaunchKernelGGL(rnn_readout, dim3(256), dim3(256), 0, stream,
                     rate_all, h2o_w, h2o_b, h2o_ctx_w, h2o_ctx_b, out0, out1);
}

// Round 2
// 3204.750 us; speedup vs baseline: 12.1721x; 12.1721x over previous
//
#include <hip/hip_runtime.h>

#define ALPHA 0.1f

constexpr int T  = 1024;
constexpr int B  = 32;
constexpr int I  = 64;
constexpr int H  = 1024;
constexpr int OF = 64;
constexpr int OC = 8;
constexpr int K  = H + I;      // 1088: h2h (1024) + i2h (64) folded into one dot
constexpr int NKK = K / 32;    // 34 k-slices of 32
constexpr int NGROUPS = 16;    // sync groups
constexpr int NMEMB   = 16;    // workgroups per group
constexpr int BPG = B / NGROUPS;        // 2 batches per group
constexpr int ROWS_PER_WG = H / NMEMB;  // 64 rows per workgroup
constexpr long long OUT1_OFF = (long long)T * B * OF;          // output_ctx offset
constexpr long long OUT2_OFF = (long long)T * B * (OF + OC);   // rate_all offset
constexpr int CNT_STRIDE = 32; // pad counters to 128B to avoid line contention

// Coherent (agent-scope, no-fence) helpers. Relaxed atomics on gfx950 emit
// global_{load,store} with sc0 sc1 — they bypass L1/L2 and hit the device
// coherence point, with NO buffer_wbl2 / buffer_inv. Ordering comes from the
// vmcnt(0) drain inside __syncthreads().
__device__ __forceinline__ void st_agent_f32(float* p, float v) {
  __hip_atomic_store(p, v, __ATOMIC_RELAXED, __HIP_MEMORY_SCOPE_AGENT);
}
__device__ __forceinline__ unsigned long long ld_agent_u64(const float* p) {
  return __hip_atomic_load((const unsigned long long*)p, __ATOMIC_RELAXED,
                           __HIP_MEMORY_SCOPE_AGENT);
}

// ---------------------------------------------------------------------------
// Recurrence: persistent kernel, 256 WGs x 512 threads.
//   group g = bid % 16 (members bid = g, g+16, ... share an XCD under
//   round-robin mapping — perf heuristic only, correctness is agent-scope).
//   member m = bid / 16 owns hidden rows [m*64, m*64+64) for the group's
//   2 batches. Weights register-stationary: w[4][34] fp32 per thread.
//   thread = (rg = tid>>5 in [0,16), ks = tid&31): rows rg*4..rg*4+3,
//   k-slice {kk*32 + ks}. r exchange via rate_all (d_out) + atomic counter.
// ---------------------------------------------------------------------------
__global__ __launch_bounds__(512, 2) void rnn_recur(
    const float* __restrict__ input_sig, const float* __restrict__ rate0,
    const float* __restrict__ i2h_w, const float* __restrict__ i2h_b,
    const float* __restrict__ h2h_w, const float* __restrict__ h2h_b,
    float* __restrict__ rate_all, unsigned* __restrict__ cnt)
{
  const int tid = threadIdx.x;
  const int bid = blockIdx.x;
  const int g  = bid & (NGROUPS - 1);
  const int m  = bid >> 4;
  const int j0 = m * ROWS_PER_WG;
  const int rg = tid >> 5;
  const int ks = tid & 31;
  const int bG = g * BPG;   // first batch of this group
  unsigned* cntp = &cnt[g * CNT_STRIDE];

  __shared__ float r_lds[BPG * K];  // [2][1088] fp32, bank = k%32 = ks

  // ---- register-stationary weights (h2h rows + i2h rows appended at k>=1024)
  float w[4][NKK];
  float bsum[4];
#pragma unroll
  for (int jj = 0; jj < 4; ++jj) {
    const int j = j0 + rg * 4 + jj;
    bsum[jj] = h2h_b[j] + i2h_b[j];
#pragma unroll
    for (int kk = 0; kk < NKK; ++kk) {
      const int k = kk * 32 + ks;
      w[jj][kk] = (kk < 32) ? h2h_w[j * H + k] : i2h_w[j * I + (k - H)];
    }
  }

  // ---- initial stage: r_{-1} = rate0 ; input_sig[0]  (plain cached loads)
  {
    const int b = tid >> 8, kq = tid & 255;
    float4 v = *(const float4*)(rate0 + (bG + b) * H + kq * 4);
    *(float4*)(&r_lds[b * K + kq * 4]) = v;
    if (tid < 32) {
      const int b2 = tid >> 4, iq = tid & 15;
      float4 u = *(const float4*)(input_sig + (long long)(bG + b2) * I + iq * 4);
      *(float4*)(&r_lds[b2 * K + H + iq * 4]) = u;
    }
  }
  __syncthreads();

  for (int t = 0; t < T; ++t) {
    float acc0[4] = {0.f, 0.f, 0.f, 0.f};
    float acc1[4] = {0.f, 0.f, 0.f, 0.f};
#pragma unroll
    for (int kk = 0; kk < NKK; ++kk) {
      const float r0 = r_lds[kk * 32 + ks];
      const float r1 = r_lds[K + kk * 32 + ks];
#pragma unroll
      for (int jj = 0; jj < 4; ++jj) {
        acc0[jj] = fmaf(w[jj][kk], r0, acc0[jj]);
        acc1[jj] = fmaf(w[jj][kk], r1, acc1[jj]);
      }
    }
    // butterfly reduce across the 32 ks lanes (masks <=16 stay in each half)
#pragma unroll
    for (int off = 16; off >= 1; off >>= 1) {
#pragma unroll
      for (int jj = 0; jj < 4; ++jj) {
        acc0[jj] += __shfl_xor(acc0[jj], off, 64);
        acc1[jj] += __shfl_xor(acc1[jj], off, 64);
      }
    }
    // 8 owner lanes per 32-lane slice apply bias + tanh + leaky update;
    // store is a coherent (sc0 sc1) write-through — visible device-wide once
    // vmcnt drains, no cache flush needed.
    if (ks < 8) {
      const int bsel = ks >> 2, jj = ks & 3;
      const float pre = (bsel == 0)
          ? ((jj == 0) ? acc0[0] : (jj == 1) ? acc0[1] : (jj == 2) ? acc0[2] : acc0[3])
          : ((jj == 0) ? acc1[0] : (jj == 1) ? acc1[1] : (jj == 2) ? acc1[2] : acc1[3]);
      const float bias = (jj == 0) ? bsum[0] : (jj == 1) ? bsum[1]
                       : (jj == 2) ? bsum[2] : bsum[3];
      const int j = j0 + rg * 4 + jj;
      const float rold = r_lds[bsel * K + j];
      const float rnew = (1.0f - ALPHA) * rold + ALPHA * tanhf(pre + bias);
      st_agent_f32(&rate_all[((long long)t * B + (bG + bsel)) * H + j], rnew);
    }

    if (t + 1 < T) {
      // barrier1: all waves done computing (r_lds reads finished) and all
      // rnew stores drained (syncthreads waits vmcnt(0) per wave).
      __syncthreads();
      // release our slice: one relaxed agent-scope add (no fence emitted)
      if (tid == 0) {
        __hip_atomic_fetch_add(cntp, 1u, __ATOMIC_RELAXED,
                               __HIP_MEMORY_SCOPE_AGENT);
      }
      // overlap: stage input_sig[t+1] (read-only, plain cached loads)
      if (tid >= 64 && tid < 96) {
        const int q = tid - 64;
        const int b2 = q >> 4, iq = q & 15;
        float4 u = *(const float4*)(input_sig +
            ((long long)(t + 1) * B + bG + b2) * I + iq * 4);
        *(float4*)(&r_lds[b2 * K + H + iq * 4]) = u;
      }
      // wait for all 16 members (relaxed agent poll: no buffer_inv)
      if (tid == 0) {
        const unsigned target = (unsigned)NMEMB * (unsigned)(t + 1);
        while (__hip_atomic_load(cntp, __ATOMIC_RELAXED,
                                 __HIP_MEMORY_SCOPE_AGENT) < target) {
          __builtin_amdgcn_s_sleep(1);
        }
      }
      __syncthreads();
      // restage r_t via coherent 64-bit loads (bypass L1/L2, read L3)
      {
        const float* src = rate_all + (long long)t * B * H + (long long)bG * H;
#pragma unroll
        for (int it = 0; it < 2; ++it) {
          const int q = it * 512 + tid;        // 1024 x 8B = 2 rows of 1024 f32
          const int b = q >> 9, uu = q & 511;
          unsigned long long v = ld_agent_u64(src + b * H + uu * 2);
          *(unsigned long long*)&r_lds[b * K + uu * 2] = v;
        }
      }
      __syncthreads();
    }
  }
}

// ---------------------------------------------------------------------------
// Readout: C[32768,72] = rate_all[32768,1024] x [h2o_w;h2o_ctx_w]^T + bias
// 256 blocks x 256 threads, 128 rows/block, h-chunks of 128 staged in LDS.
// Thread tile: 4 rows x 9 outputs (rb = tid&31 row-lane, og = tid>>5).
// ---------------------------------------------------------------------------
__global__ __launch_bounds__(256) void rnn_readout(
    const float* __restrict__ rate_all,
    const float* __restrict__ h2o_w, const float* __restrict__ h2o_b,
    const float* __restrict__ h2o_ctx_w, const float* __restrict__ h2o_ctx_b,
    float* __restrict__ out0, float* __restrict__ out1)
{
  constexpr int RB = 128;   // rows per block
  constexpr int HC = 128;   // h chunk
  constexpr int SR = HC + 1; // padded stride -> conflict-free reads
  __shared__ float rl[RB * SR];   // 66 KB
  __shared__ float wl[72 * SR];   // 37 KB

  const int tid = threadIdx.x;
  const long long row0 = (long long)blockIdx.x * RB;
  const int rb = tid & 31, og = tid >> 5;

  float acc[4][9];
#pragma unroll
  for (int c = 0; c < 4; ++c)
#pragma unroll
    for (int i = 0; i < 9; ++i) acc[c][i] = 0.f;

  for (int hc = 0; hc < H / HC; ++hc) {
    // stage r chunk: 128 rows x 128 h = 4096 float4, 16 per thread
#pragma unroll
    for (int i = 0; i < 16; ++i) {
      const int q = i * 256 + tid;
      const int row = q >> 5, hq = q & 31;
      float4 v = *(const float4*)(rate_all + (row0 + row) * H + hc * HC + hq * 4);
      float* d = &rl[row * SR + hq * 4];
      d[0] = v.x; d[1] = v.y; d[2] = v.z; d[3] = v.w;
    }
    // stage w chunk: 72 x 128 = 2304 float4, 9 per thread
#pragma unroll
    for (int i = 0; i < 9; ++i) {
      const int q = i * 256 + tid;
      const int o = q >> 5, hq = q & 31;
      const float* src = (o < OF) ? (h2o_w + (long long)o * H)
                                  : (h2o_ctx_w + (long long)(o - OF) * H);
      float4 v = *(const float4*)(src + hc * HC + hq * 4);
      float* d = &wl[o * SR + hq * 4];
      d[0] = v.x; d[1] = v.y; d[2] = v.z; d[3] = v.w;
    }
    __syncthreads();

#pragma unroll 4
    for (int h = 0; h < HC; ++h) {
      const float r0 = rl[(rb)      * SR + h];
      const float r1 = rl[(rb + 32) * SR + h];
      const float r2 = rl[(rb + 64) * SR + h];
      const float r3 = rl[(rb + 96) * SR + h];
#pragma unroll
      for (int i = 0; i < 9; ++i) {
        const float wv = wl[(og * 9 + i) * SR + h];
        acc[0][i] = fmaf(r0, wv, acc[0][i]);
        acc[1][i] = fmaf(r1, wv, acc[1][i]);
        acc[2][i] = fmaf(r2, wv, acc[2][i]);
        acc[3][i] = fmaf(r3, wv, acc[3][i]);
      }
    }
    __syncthreads();
  }

#pragma unroll
  for (int c = 0; c < 4; ++c) {
    const long long row = row0 + rb + 32 * c;
#pragma unroll
    for (int i = 0; i < 9; ++i) {
      const int o = og * 9 + i;
      if (o < OF) out0[row * OF + o] = acc[c][i] + h2o_b[o];
      else        out1[row * OC + (o - OF)] = acc[c][i] + h2o_ctx_b[o - OF];
    }
  }
}

extern "C" void kernel_launch(void* const* d_in, const int* in_sizes, int n_in,
                              void* d_out, int out_size, void* d_ws, size_t ws_size,
                              hipStream_t stream) {
  (void)in_sizes; (void)n_in; (void)d_ws; (void)ws_size; (void)out_size;
  const float* input_sig = (const float*)d_in[0];
  const float* rate0     = (const float*)d_in[1];
  const float* i2h_w     = (const float*)d_in[2];
  const float* i2h_b     = (const float*)d_in[3];
  const float* h2h_w     = (const float*)d_in[4];
  const float* h2h_b     = (const float*)d_in[5];
  const float* h2o_w     = (const float*)d_in[6];
  const float* h2o_b     = (const float*)d_in[7];
  const float* h2o_ctx_w = (const float*)d_in[8];
  const float* h2o_ctx_b = (const float*)d_in[9];

  float* out      = (float*)d_out;
  float* out0     = out;
  float* out1     = out + OUT1_OFF;
  float* rate_all = out + OUT2_OFF;
  // sync counters live in the first 2KB of out0 during the recurrence;
  // the readout kernel overwrites that region with real outputs afterwards.
  unsigned* cnt = (unsigned*)d_out;

  hipMemsetAsync(d_out, 0, NGROUPS * CNT_STRIDE * sizeof(unsigned), stream);
  hipLaunchKernelGGL(rnn_recur, dim3(NGROUPS * NMEMB), dim3(512), 0, stream,
                     input_sig, rate0, i2h_w, i2h_b, h2h_w, h2h_b, rate_all, cnt);
  hipLaunchKernelGGL(rnn_readout, dim3(256), dim3(256), 0, stream,
                     rate_all, h2o_w, h2o_b, h2o_ctx_w, h2o_ctx_b, out0, out1);
}